// Round 1
// baseline (1149.122 us; speedup 1.0000x reference)
//
#include <hip/hip_runtime.h>
#include <hip/hip_bf16.h>

#define B_ 4
#define T_ 4096
#define C_ 1024
#define H_ 64

// ============================================================================
// Projection GEMM: out[M=B*T][64] = x[M][C] @ W[C][64], one W per blockIdx.y
// BM=64, BN=64, BK=32, 256 threads, 4x4 micro-tile per thread.
// ============================================================================
__global__ __launch_bounds__(256, 4)
void proj_kernel(const float* __restrict__ x,
                 const float* __restrict__ Wq,
                 const float* __restrict__ Wk,
                 const float* __restrict__ Wv,
                 float* __restrict__ q, float* __restrict__ k, float* __restrict__ v)
{
    __shared__ __align__(16) float As[32][68];  // x tile transposed [k][m], pad 68 (16B-aligned rows)
    __shared__ __align__(16) float Bs[32][64];  // W tile [k][n]

    const int m0  = blockIdx.x * 64;
    const int mat = blockIdx.y;
    const float* W  = (mat == 0) ? Wq : (mat == 1) ? Wk : Wv;
    float* out      = (mat == 0) ? q  : (mat == 1) ? k  : v;

    const int tid = threadIdx.x;
    const int tx  = tid & 15;   // n/4
    const int ty  = tid >> 4;   // m/4

    float acc[4][4];
    #pragma unroll
    for (int i = 0; i < 4; ++i)
        #pragma unroll
        for (int j = 0; j < 4; ++j) acc[i][j] = 0.f;

    for (int k0 = 0; k0 < C_; k0 += 32) {
        // stage A: 64 rows x 32 k = 512 float4, 2 per thread; transpose into As
        #pragma unroll
        for (int i = 0; i < 2; ++i) {
            int f   = tid + i * 256;
            int row = f >> 3;
            int kc4 = f & 7;
            float4 a = *(const float4*)&x[(size_t)(m0 + row) * C_ + k0 + kc4 * 4];
            As[kc4 * 4 + 0][row] = a.x;
            As[kc4 * 4 + 1][row] = a.y;
            As[kc4 * 4 + 2][row] = a.z;
            As[kc4 * 4 + 3][row] = a.w;
        }
        // stage B: 32 rows x 64 n = 512 float4, 2 per thread
        #pragma unroll
        for (int i = 0; i < 2; ++i) {
            int f   = tid + i * 256;
            int row = f >> 4;
            int c4  = f & 15;
            *(float4*)&Bs[row][c4 * 4] = *(const float4*)&W[(size_t)(k0 + row) * H_ + c4 * 4];
        }
        __syncthreads();

        #pragma unroll
        for (int kk = 0; kk < 32; ++kk) {
            float4 a = *(const float4*)&As[kk][ty * 4];
            float4 b = *(const float4*)&Bs[kk][tx * 4];
            float av[4] = {a.x, a.y, a.z, a.w};
            float bv[4] = {b.x, b.y, b.z, b.w};
            #pragma unroll
            for (int i = 0; i < 4; ++i)
                #pragma unroll
                for (int j = 0; j < 4; ++j)
                    acc[i][j] = fmaf(av[i], bv[j], acc[i][j]);
        }
        __syncthreads();
    }

    #pragma unroll
    for (int i = 0; i < 4; ++i) {
        float4 st = make_float4(acc[i][0], acc[i][1], acc[i][2], acc[i][3]);
        *(float4*)&out[(size_t)(m0 + ty * 4 + i) * H_ + tx * 4] = st;
    }
}

// ============================================================================
// Flash attention (causal), fp32. One q-row per thread, 8-way key split.
// Block: 256 threads = 32 q rows x 8 splits. Grid: (T/32, B).
// K/V read straight from global (L2-resident: 2 MB per batch).
// ============================================================================
__global__ __launch_bounds__(256, 2)
void attn_kernel(const float* __restrict__ Q, const float* __restrict__ K,
                 const float* __restrict__ V, float* __restrict__ out)
{
    const int bx = blockIdx.x;
    const int b  = blockIdx.y;
    // pair small and large q-tiles on adjacent blocks for load balance
    const int tile = (bx & 1) ? (127 - (bx >> 1)) : (bx >> 1);
    const int t0   = tile * 32;

    const int tid = threadIdx.x;
    const int r   = tid & 31;   // q row within tile
    const int p   = tid >> 5;   // key split 0..7
    const int t   = t0 + r;     // my q row

    const float* Qrow = Q + ((size_t)b * T_ + t) * H_;
    float4 q4[16];
    #pragma unroll
    for (int d = 0; d < 16; ++d) q4[d] = ((const float4*)Qrow)[d];

    float4 o4[16];
    #pragma unroll
    for (int d = 0; d < 16; ++d) o4[d] = make_float4(0.f, 0.f, 0.f, 0.f);
    float m = -1e30f, l = 0.f;

    const int NTL  = tile + 1;            // key tiles needed by this block
    const int base = NTL >> 3, rem = NTL & 7;
    const int myStart = p * base + min(p, rem);
    const int myCnt   = base + (p < rem ? 1 : 0);

    const float* Kb = K + (size_t)b * T_ * H_;
    const float* Vb = V + (size_t)b * T_ * H_;

    for (int tt = 0; tt < myCnt; ++tt) {
        const int j0 = (myStart + tt) * 32;
        if (j0 > t) break;  // strictly later tiles are fully masked for me

        const float4* Kp = (const float4*)(Kb + (size_t)j0 * H_);
        float s[32];
        #pragma unroll 2
        for (int j = 0; j < 32; ++j) {
            float s0 = 0.f, s1 = 0.f, s2 = 0.f, s3 = 0.f;
            #pragma unroll
            for (int d = 0; d < 16; ++d) {
                float4 kk = Kp[j * 16 + d];
                s0 = fmaf(q4[d].x, kk.x, s0);
                s1 = fmaf(q4[d].y, kk.y, s1);
                s2 = fmaf(q4[d].z, kk.z, s2);
                s3 = fmaf(q4[d].w, kk.w, s3);
            }
            float sj = (s0 + s1) + (s2 + s3);
            s[j] = (j0 + j <= t) ? sj * 0.125f : -1e30f;
        }

        float tmax = s[0];
        #pragma unroll
        for (int j = 1; j < 32; ++j) tmax = fmaxf(tmax, s[j]);
        float mnew = fmaxf(m, tmax);
        float sc = __expf(m - mnew);   // m==-1e30 first time -> 0
        l *= sc;
        #pragma unroll
        for (int d = 0; d < 16; ++d) {
            o4[d].x *= sc; o4[d].y *= sc; o4[d].z *= sc; o4[d].w *= sc;
        }

        const float4* Vp = (const float4*)(Vb + (size_t)j0 * H_);
        #pragma unroll 2
        for (int j = 0; j < 32; ++j) {
            float pj = __expf(s[j] - mnew);   // masked: exp(-1e30 - m) -> 0
            l += pj;
            #pragma unroll
            for (int d = 0; d < 16; ++d) {
                float4 vv = Vp[j * 16 + d];
                o4[d].x = fmaf(pj, vv.x, o4[d].x);
                o4[d].y = fmaf(pj, vv.y, o4[d].y);
                o4[d].z = fmaf(pj, vv.z, o4[d].z);
                o4[d].w = fmaf(pj, vv.w, o4[d].w);
            }
        }
        m = mnew;
    }

    // ---- merge the 8 splits per row: tree reduction through LDS ----
    __shared__ __align__(16) float smo[4][32][72];  // pad 72: 16B-aligned, spreads banks
    __shared__ float smm[4][32], sml[4][32];

    #pragma unroll
    for (int step = 4; step >= 1; step >>= 1) {
        if (p >= step && p < 2 * step) {
            smm[p - step][r] = m;
            sml[p - step][r] = l;
            #pragma unroll
            for (int d = 0; d < 16; ++d)
                *(float4*)&smo[p - step][r][d * 4] = o4[d];
        }
        __syncthreads();
        if (p < step) {
            float m2 = smm[p][r], l2 = sml[p][r];
            float M  = fmaxf(m, m2);
            float w1 = __expf(m - M);   // both -1e30 -> exp(0)=1, l stays 0: safe
            float w2 = __expf(m2 - M);
            l = w1 * l + w2 * l2;
            #pragma unroll
            for (int d = 0; d < 16; ++d) {
                float4 o2 = *(const float4*)&smo[p][r][d * 4];
                o4[d].x = w1 * o4[d].x + w2 * o2.x;
                o4[d].y = w1 * o4[d].y + w2 * o2.y;
                o4[d].z = w1 * o4[d].z + w2 * o2.z;
                o4[d].w = w1 * o4[d].w + w2 * o2.w;
            }
            m = M;
        }
        __syncthreads();
    }

    if (p == 0) {
        float inv = 1.0f / l;
        float* orow = out + ((size_t)b * T_ + t) * H_;
        #pragma unroll
        for (int d = 0; d < 16; ++d) {
            float4 o = o4[d];
            o.x *= inv; o.y *= inv; o.z *= inv; o.w *= inv;
            ((float4*)orow)[d] = o;
        }
    }
}

extern "C" void kernel_launch(void* const* d_in, const int* in_sizes, int n_in,
                              void* d_out, int out_size, void* d_ws, size_t ws_size,
                              hipStream_t stream) {
    const float* x  = (const float*)d_in[0];
    const float* Wq = (const float*)d_in[1];
    const float* Wk = (const float*)d_in[2];
    const float* Wv = (const float*)d_in[3];
    float* out = (float*)d_out;

    const size_t BTH = (size_t)B_ * T_ * H_;
    float* q = (float*)d_ws;
    float* k = q + BTH;
    float* v = k + BTH;

    dim3 gp(B_ * T_ / 64, 3);
    proj_kernel<<<gp, 256, 0, stream>>>(x, Wq, Wk, Wv, q, k, v);

    dim3 ga(T_ / 32, B_);
    attn_kernel<<<ga, 256, 0, stream>>>(q, k, v, out);
}

// Round 2
// 544.772 us; speedup vs baseline: 2.1094x; 2.1094x over previous
//
#include <hip/hip_runtime.h>
#include <hip/hip_bf16.h>

#define B_ 4
#define T_ 4096
#define C_ 1024
#define H_ 64

// ============================================================================
// Projection GEMM: out[M=B*T][64] = x[M][C] @ W[C][64], one W per blockIdx.y
// BM=64, BN=64, BK=32, 256 threads, 4x4 micro-tile per thread. (unchanged)
// ============================================================================
__global__ __launch_bounds__(256, 4)
void proj_kernel(const float* __restrict__ x,
                 const float* __restrict__ Wq,
                 const float* __restrict__ Wk,
                 const float* __restrict__ Wv,
                 float* __restrict__ q, float* __restrict__ k, float* __restrict__ v)
{
    __shared__ __align__(16) float As[32][68];
    __shared__ __align__(16) float Bs[32][64];

    const int m0  = blockIdx.x * 64;
    const int mat = blockIdx.y;
    const float* W  = (mat == 0) ? Wq : (mat == 1) ? Wk : Wv;
    float* out      = (mat == 0) ? q  : (mat == 1) ? k  : v;

    const int tid = threadIdx.x;
    const int tx  = tid & 15;
    const int ty  = tid >> 4;

    float acc[4][4];
    #pragma unroll
    for (int i = 0; i < 4; ++i)
        #pragma unroll
        for (int j = 0; j < 4; ++j) acc[i][j] = 0.f;

    for (int k0 = 0; k0 < C_; k0 += 32) {
        #pragma unroll
        for (int i = 0; i < 2; ++i) {
            int f   = tid + i * 256;
            int row = f >> 3;
            int kc4 = f & 7;
            float4 a = *(const float4*)&x[(size_t)(m0 + row) * C_ + k0 + kc4 * 4];
            As[kc4 * 4 + 0][row] = a.x;
            As[kc4 * 4 + 1][row] = a.y;
            As[kc4 * 4 + 2][row] = a.z;
            As[kc4 * 4 + 3][row] = a.w;
        }
        #pragma unroll
        for (int i = 0; i < 2; ++i) {
            int f   = tid + i * 256;
            int row = f >> 4;
            int c4  = f & 15;
            *(float4*)&Bs[row][c4 * 4] = *(const float4*)&W[(size_t)(k0 + row) * H_ + c4 * 4];
        }
        __syncthreads();

        #pragma unroll
        for (int kk = 0; kk < 32; ++kk) {
            float4 a = *(const float4*)&As[kk][ty * 4];
            float4 b = *(const float4*)&Bs[kk][tx * 4];
            float av[4] = {a.x, a.y, a.z, a.w};
            float bv[4] = {b.x, b.y, b.z, b.w};
            #pragma unroll
            for (int i = 0; i < 4; ++i)
                #pragma unroll
                for (int j = 0; j < 4; ++j)
                    acc[i][j] = fmaf(av[i], bv[j], acc[i][j]);
        }
        __syncthreads();
    }

    #pragma unroll
    for (int i = 0; i < 4; ++i) {
        float4 st = make_float4(acc[i][0], acc[i][1], acc[i][2], acc[i][3]);
        *(float4*)&out[(size_t)(m0 + ty * 4 + i) * H_ + tx * 4] = st;
    }
}

// ============================================================================
// Flash attention (causal), fp32, LDS-staged K/V with broadcast reads.
// Block: 256 threads = 8 key-splits x 32 q-rows. Each thread owns one q row
// (full 64 dims in registers). Split s processes key tiles s, s+8, s+16, ...
// (KT=16 keys each) with its own online softmax; tree-merge at the end.
// Grid: (T/32, B). LDS: K+V tiles = 64 KB -> 2 blocks/CU.
// ============================================================================
#define KT      16
#define SPLITS  8
#define ROWS    32

__global__ __launch_bounds__(256, 2)
void attn_kernel(const float* __restrict__ Q, const float* __restrict__ K,
                 const float* __restrict__ V, float* __restrict__ out)
{
    __shared__ __align__(16) float lds[SPLITS * KT * 64 * 2];  // 64 KB
    float (*Ks)[KT][64] = (float (*)[KT][64])lds;
    float (*Vs)[KT][64] = (float (*)[KT][64])(lds + SPLITS * KT * 64);

    const int bx = blockIdx.x;
    const int b  = blockIdx.y;
    // pair small and large q-tiles on adjacent blocks for load balance
    const int tile = (bx & 1) ? (127 - (bx >> 1)) : (bx >> 1);
    const int t0   = tile * ROWS;

    const int tid   = threadIdx.x;
    const int r     = tid & 31;    // q row within tile
    const int split = tid >> 5;    // key split 0..7
    const int t     = t0 + r;      // my q row

    const float* Qrow = Q + ((size_t)b * T_ + t) * H_;
    float4 q4[16];
    #pragma unroll
    for (int d = 0; d < 16; ++d) q4[d] = ((const float4*)Qrow)[d];

    float4 o4[16];
    #pragma unroll
    for (int d = 0; d < 16; ++d) o4[d] = make_float4(0.f, 0.f, 0.f, 0.f);
    float m = -1e30f, l = 0.f;

    const float* Kb = K + (size_t)b * T_ * H_;
    const float* Vb = V + (size_t)b * T_ * H_;

    const int nt    = 2 * (tile + 1);              // 16-key tiles needed
    const int itmax = (nt + SPLITS - 1) / SPLITS;

    for (int it = 0; it < itmax; ++it) {
        const int  tidx   = it * SPLITS + split;
        const bool active = (tidx < nt);
        const int  j0     = tidx * KT;

        __syncthreads();   // previous tile's compute done before overwrite
        if (active) {
            const float4* Kg = (const float4*)(Kb + (size_t)j0 * H_);
            const float4* Vg = (const float4*)(Vb + (size_t)j0 * H_);
            float4* KsD = (float4*)&Ks[split][0][0];
            float4* VsD = (float4*)&Vs[split][0][0];
            #pragma unroll
            for (int i = 0; i < 8; ++i) {
                int f = r + i * 32;      // 256 float4 = KT*64 floats
                KsD[f] = Kg[f];
                VsD[f] = Vg[f];
            }
        }
        __syncthreads();

        if (active && j0 <= t) {
            float s_arr[KT];
            #pragma unroll 4
            for (int j = 0; j < KT; ++j) {
                const float4* Kj = (const float4*)&Ks[split][j][0];
                float a0 = 0.f, a1 = 0.f, a2 = 0.f, a3 = 0.f;
                #pragma unroll
                for (int d = 0; d < 16; ++d) {
                    float4 kk = Kj[d];
                    a0 = fmaf(q4[d].x, kk.x, a0);
                    a1 = fmaf(q4[d].y, kk.y, a1);
                    a2 = fmaf(q4[d].z, kk.z, a2);
                    a3 = fmaf(q4[d].w, kk.w, a3);
                }
                float sj = (a0 + a1) + (a2 + a3);
                s_arr[j] = (j0 + j <= t) ? sj * 0.125f : -1e30f;
            }

            float tmax = s_arr[0];
            #pragma unroll
            for (int j = 1; j < KT; ++j) tmax = fmaxf(tmax, s_arr[j]);
            float mnew = fmaxf(m, tmax);
            float sc = __expf(m - mnew);   // first tile: exp(-1e30-x)=0
            l *= sc;
            #pragma unroll
            for (int d = 0; d < 16; ++d) {
                o4[d].x *= sc; o4[d].y *= sc; o4[d].z *= sc; o4[d].w *= sc;
            }

            #pragma unroll 4
            for (int j = 0; j < KT; ++j) {
                float pj = __expf(s_arr[j] - mnew);  // masked -> exp(-huge)=0
                l += pj;
                const float4* Vj = (const float4*)&Vs[split][j][0];
                #pragma unroll
                for (int d = 0; d < 16; ++d) {
                    float4 vv = Vj[d];
                    o4[d].x = fmaf(pj, vv.x, o4[d].x);
                    o4[d].y = fmaf(pj, vv.y, o4[d].y);
                    o4[d].z = fmaf(pj, vv.z, o4[d].z);
                    o4[d].w = fmaf(pj, vv.w, o4[d].w);
                }
            }
            m = mnew;
        }
    }

    // ---- merge the 8 splits per row: tree reduction through LDS ----
    // Reuse the K/V LDS (all compute done, barrier-separated).
    // Layout: mo[slot][68] with slot = sp*32 + r (68-float stride, 16B-aligned);
    // ml at offset 4*32*68.
    float* mo = lds;
    float* ml = lds + 4 * 32 * 68;

    #pragma unroll
    for (int step = 4; step >= 1; step >>= 1) {
        __syncthreads();
        if (split >= step && split < 2 * step) {
            int slot = (split - step) * 32 + r;
            #pragma unroll
            for (int d = 0; d < 16; ++d)
                *(float4*)&mo[slot * 68 + d * 4] = o4[d];
            ml[slot * 2 + 0] = m;
            ml[slot * 2 + 1] = l;
        }
        __syncthreads();
        if (split < step) {
            int slot = split * 32 + r;
            float m2 = ml[slot * 2 + 0];
            float l2 = ml[slot * 2 + 1];
            float M  = fmaxf(m, m2);
            float w1 = __expf(m - M);    // both empty (-1e30): w=1, l stays 0
            float w2 = __expf(m2 - M);
            l = w1 * l + w2 * l2;
            #pragma unroll
            for (int d = 0; d < 16; ++d) {
                float4 o2 = *(const float4*)&mo[slot * 68 + d * 4];
                o4[d].x = w1 * o4[d].x + w2 * o2.x;
                o4[d].y = w1 * o4[d].y + w2 * o2.y;
                o4[d].z = w1 * o4[d].z + w2 * o2.z;
                o4[d].w = w1 * o4[d].w + w2 * o2.w;
            }
            m = M;
        }
    }

    if (split == 0) {
        float inv = 1.0f / l;            // l>0: split 0 always has key 0
        float* orow = out + ((size_t)b * T_ + t) * H_;
        #pragma unroll
        for (int d = 0; d < 16; ++d) {
            float4 o = o4[d];
            o.x *= inv; o.y *= inv; o.z *= inv; o.w *= inv;
            ((float4*)orow)[d] = o;
        }
    }
}

extern "C" void kernel_launch(void* const* d_in, const int* in_sizes, int n_in,
                              void* d_out, int out_size, void* d_ws, size_t ws_size,
                              hipStream_t stream) {
    const float* x  = (const float*)d_in[0];
    const float* Wq = (const float*)d_in[1];
    const float* Wk = (const float*)d_in[2];
    const float* Wv = (const float*)d_in[3];
    float* out = (float*)d_out;

    const size_t BTH = (size_t)B_ * T_ * H_;
    float* q = (float*)d_ws;
    float* k = q + BTH;
    float* v = k + BTH;

    dim3 gp(B_ * T_ / 64, 3);
    proj_kernel<<<gp, 256, 0, stream>>>(x, Wq, Wk, Wv, q, k, v);

    dim3 ga(T_ / 32, B_);
    attn_kernel<<<ga, 256, 0, stream>>>(q, k, v, out);
}